// Round 1
// baseline (4060.958 us; speedup 1.0000x reference)
//
#include <hip/hip_runtime.h>
#include <math.h>

// Problem: B=64, T=512, I=128, H=1024, O=128; gates order i,j,f,o; relu activations.
#define Bsz 64
#define Tn  512
#define In  128
#define Hn  1024
#define KT  1152      // I + H
#define NBLK 128      // persistent blocks; each owns 8 hidden cols (x4 gates = 32 cols)

// Sync area: per-block step flags, one per block, packed 4-per-16B so a consumer
// lane can cover 4 producer blocks with one dwordx4 sc0|sc1 load.
//   flag[blk] at byte 16*... NO: flag[blk] at byte 4*blk within 16B groups -> word index blk.
//   We store flags at S word index blk*4? See fsrd usage: flag[blk] lives at byte blk*4
//   grouped as 4 flags / 16B: group g covers blocks 4g..4g+3 (h cols [32g,32g+32)).

typedef __attribute__((ext_vector_type(8))) short bf16x8;   // 8 bf16 = 4 VGPRs (MFMA A/B frag)
typedef __attribute__((ext_vector_type(4))) short s16x4;
typedef __attribute__((ext_vector_type(4))) float f32x4;
typedef __attribute__((ext_vector_type(4))) int   i32x4;

// Raw buffer ops, cpol 17 = SC0|SC1 on gfx950 -> write-through / read-through at the
// IF/MALL coherence point (cross-XCD visible without cache-walk fences). [R2/R3-proven]
__device__ void llvm_amdgcn_raw_buffer_store_v4i32(i32x4 vdata, i32x4 srsrc, int voffset, int soffset, int cpol) __asm("llvm.amdgcn.raw.buffer.store.v4i32");
__device__ void llvm_amdgcn_raw_buffer_store_i32(int vdata, i32x4 srsrc, int voffset, int soffset, int cpol) __asm("llvm.amdgcn.raw.buffer.store.i32");
__device__ i32x4 llvm_amdgcn_raw_buffer_load_v4i32(i32x4 srsrc, int voffset, int soffset, int cpol) __asm("llvm.amdgcn.raw.buffer.load.v4i32");

__device__ __forceinline__ i32x4 make_srd(const void* p, int bytes) {
  i32x4 r;
  r.x = (int)(unsigned)(unsigned long long)p;
  r.y = (int)((unsigned long long)p >> 32);   // stride = 0
  r.z = bytes;                                // num_records (bytes when stride==0)
  r.w = 0x00020000;                           // raw dword access
  return r;
}

__device__ __forceinline__ unsigned short f2bf(float f) {
  union { float f; unsigned u; } x; x.f = f;
  unsigned r = x.u + 0x7FFFu + ((x.u >> 16) & 1u);   // RNE
  return (unsigned short)(r >> 16);
}
__device__ __forceinline__ float sigmoidf_(float x) { return 1.0f / (1.0f + __expf(-x)); }

// ---------------- prep: X (fp32) -> Xb (bf16), elementwise ----------------
__global__ __launch_bounds__(256) void cast_x_kernel(const float* __restrict__ in,
                                                     unsigned short* __restrict__ out) {
  int i = blockIdx.x * 256 + threadIdx.x;
  f32x4 v = ((const f32x4*)in)[i];
  s16x4 o;
  o.x = (short)f2bf(v.x); o.y = (short)f2bf(v.y);
  o.z = (short)f2bf(v.z); o.w = (short)f2bf(v.w);
  ((s16x4*)out)[i] = o;
}

// -------- prep: transpose+cast fp32 [R][C] -> bf16 [C][ldo] (64x64 LDS tiles) --------
__global__ __launch_bounds__(256) void transpose_cast_kernel(const float* __restrict__ in,
                                                             unsigned short* __restrict__ out,
                                                             int R, int C, int ldo, int tilesR) {
  __shared__ unsigned short tile[64][73];
  int br = blockIdx.x % tilesR, bc = blockIdx.x / tilesR;
  int r0 = br << 6, c0 = bc << 6;
  for (int e = threadIdx.x; e < 4096; e += 256) {
    int r = e >> 6, c = e & 63;
    tile[r][c] = f2bf(in[(size_t)(r0 + r) * C + (c0 + c)]);
  }
  __syncthreads();
  for (int e = threadIdx.x; e < 4096; e += 256) {
    int c = e >> 6, r = e & 63;
    out[(size_t)(c0 + c) * ldo + (r0 + r)] = tile[r][c];
  }
}

// ---------------- persistent LSTM recurrence ----------------
// Block blk owns hidden cols j in [blk*8, blk*8+8), gate cols {j, H+j, 2H+j, 3H+j}.
// 8 waves = (2 batch-halves mh) x (4 K-quarters kq); B-frags register-resident.
//
// Sync redesign (this round): NO atomics, NO all-wave store drain.
//   produce: epilogue threads drop h(t) into LDS Hl[64][8]; after the barrier,
//            WAVE 0 alone emits 64 coalesced 16B sc0|sc1 stores (one per batch row:
//            the block's 8 cols are contiguous in hs), waits ITS OWN vmcnt(0)
//            (stores are MALL-acked => globally visible), then lane 0 posts the
//            per-block flag = t+1 (sc0|sc1 write-through store).
//   wait:    each consumer WAVE polls the per-block flags of the 20/36 producer
//            blocks covering its h k-slice: flags packed 4-per-16B, so 5/9 lanes
//            each load one dwordx4 (sc0|sc1), min-of-4, ballot; s_sleep backoff.
// Consumer h loads stay PLAIN -> per-XCD L2-shared, virgin t-lines.
__global__ __launch_bounds__(512, 1) void lstm_kernel(
    const unsigned short* __restrict__ Xb,    // [64][512][128] bf16
    const unsigned short* __restrict__ WkT,   // [4096][1152]  bf16 (col-major-in-k)
    const float* __restrict__ bias,           // [4096]
    unsigned short* __restrict__ hs,          // [512][64][1024] bf16 (output history)
    unsigned* __restrict__ S)                 // sync area (flags: 128 x 4B, zeroed)
{
  __shared__ float Z4[4][64][36];             // per-kq partials [kq][batch][32 cols], ld 36
  __shared__ __align__(16) unsigned short Hl[64][8];   // h(t) gather buffer (16B rows)
  const int tid = threadIdx.x;
  const int blk = blockIdx.x;
  const int w   = tid >> 6;
  const int mh  = w & 1;                      // batch half (32 rows)
  const int kq  = w >> 1;                     // K quarter (288 of 1152)
  const int l   = tid & 63, q = l >> 4, n16 = l & 15;

  const i32x4 hsrd = make_srd(hs, Tn * Bsz * Hn * 2);
  const i32x4 fsrd = make_srd(S, 2048);       // 128 flags x 4B, grouped 4/16B

  // ---- load register-resident B fragments (once) ----
  bf16x8 Bf[2][9];
#pragma unroll
  for (int nt = 0; nt < 2; ++nt) {
    int cl   = nt * 16 + n16;                                  // local col 0..31
    int gcol = (cl >> 3) * Hn + blk * 8 + (cl & 7);            // gate*1024 + j
    const unsigned short* bp = WkT + (size_t)gcol * KT + kq * 288 + q * 8;
#pragma unroll
    for (int ks = 0; ks < 9; ++ks)
      Bf[nt][ks] = *(const bf16x8*)(bp + ks * 32);
  }

  // ---- epilogue constants: thread = (batch eb, col ej) ----
  const int eb = tid >> 3, ej = tid & 7;
  const float bi  = bias[           blk * 8 + ej];
  const float bg  = bias[    Hn   + blk * 8 + ej];
  const float bfg = bias[2 * Hn   + blk * 8 + ej] + 1.0f;      // TF forget bias
  const float bo  = bias[3 * Hn   + blk * 8 + ej];
  float cst = 0.0f;                                            // cell state, persistent in VGPR

  const int b0 = mh * 32 + n16;                                // A rows (two 16-batch tiles)
  const int b1 = b0 + 16;

  // ---- per-wave producer flag-groups (group g = blocks 4g..4g+3 = h cols [32g,32g+32)) ----
  // wave kq h-cols: kq0 [0,160)->groups 0..4; kq1 [160,448)->5..13; kq2 [448,736)->14..22;
  //                 kq3 [736,1024)->23..31
  const int gbase = (kq == 0) ? 0 : (5 + (kq - 1) * 9);
  const int ng    = kq ? 9 : 5;

  for (int t = 0; t < Tn; ++t) {
    f32x4 a00 = {0,0,0,0}, a01 = {0,0,0,0}, a10 = {0,0,0,0}, a11 = {0,0,0,0};

    if (t > 0) {
      // x-part A-frags don't depend on flags: prefetch before polling (kq0 only)
      bf16x8 X0[4], X1[4];
      if (kq == 0) {
#pragma unroll
        for (int ks = 0; ks < 4; ++ks) {
          X0[ks] = *(const bf16x8*)(Xb + ((size_t)b0 * Tn + t) * In + ks * 32 + q * 8);
          X1[ks] = *(const bf16x8*)(Xb + ((size_t)b1 * Tn + t) * In + ks * 32 + q * 8);
        }
      }
      // wave-local wait: all producer blocks of this wave's k-slice at step >= t
      for (;;) {
        asm volatile("" ::: "memory");        // defeat LICM: re-load flags every iter
        unsigned m = 0xFFFFFFFFu;
        if (l < ng) {
          i32x4 v = llvm_amdgcn_raw_buffer_load_v4i32(fsrd, (gbase + l) << 4, 0, 17);
          unsigned ma = (unsigned)v.x, mb = (unsigned)v.y;
          unsigned mc = (unsigned)v.z, md = (unsigned)v.w;
          ma = ma < mb ? ma : mb;
          mc = mc < md ? mc : md;
          m  = ma < mc ? ma : mc;
        }
        if (__ballot(m >= (unsigned)t) == ~0ull) break;
        __builtin_amdgcn_s_sleep(1);          // ~64cy backoff: pace the MALL poll storm
      }
      const unsigned short* hrow = hs + (size_t)(t - 1) * (Bsz * Hn);
#pragma unroll
      for (int ks = 0; ks < 9; ++ks) {
        bf16x8 A0, A1;
        if (kq == 0 && ks < 4) {
          A0 = X0[ks]; A1 = X1[ks];
        } else {
          int kh = kq * 288 + ks * 32 - 128 + q * 8;           // h col
          A0 = *(const bf16x8*)(hrow + (size_t)b0 * Hn + kh);
          A1 = *(const bf16x8*)(hrow + (size_t)b1 * Hn + kh);
        }
        a00 = __builtin_amdgcn_mfma_f32_16x16x32_bf16(A0, Bf[0][ks], a00, 0, 0, 0);
        a01 = __builtin_amdgcn_mfma_f32_16x16x32_bf16(A0, Bf[1][ks], a01, 0, 0, 0);
        a10 = __builtin_amdgcn_mfma_f32_16x16x32_bf16(A1, Bf[0][ks], a10, 0, 0, 0);
        a11 = __builtin_amdgcn_mfma_f32_16x16x32_bf16(A1, Bf[1][ks], a11, 0, 0, 0);
      }
    } else if (kq == 0) {                                      // t==0: h==0, x-part only
#pragma unroll
      for (int ks = 0; ks < 4; ++ks) {
        bf16x8 A0 = *(const bf16x8*)(Xb + ((size_t)b0 * Tn) * In + ks * 32 + q * 8);
        bf16x8 A1 = *(const bf16x8*)(Xb + ((size_t)b1 * Tn) * In + ks * 32 + q * 8);
        a00 = __builtin_amdgcn_mfma_f32_16x16x32_bf16(A0, Bf[0][ks], a00, 0, 0, 0);
        a01 = __builtin_amdgcn_mfma_f32_16x16x32_bf16(A0, Bf[1][ks], a01, 0, 0, 0);
        a10 = __builtin_amdgcn_mfma_f32_16x16x32_bf16(A1, Bf[0][ks], a10, 0, 0, 0);
        a11 = __builtin_amdgcn_mfma_f32_16x16x32_bf16(A1, Bf[1][ks], a11, 0, 0, 0);
      }
    }

    // ---- write per-kq partials (no atomics) ----
#pragma unroll
    for (int r = 0; r < 4; ++r) {
      int row = mh * 32 + q * 4 + r;
      Z4[kq][row     ][     n16] = a00[r];
      Z4[kq][row     ][16 + n16] = a01[r];
      Z4[kq][row + 16][     n16] = a10[r];
      Z4[kq][row + 16][16 + n16] = a11[r];
    }
    __syncthreads();                                           // (A) Z4 ready

    // ---- gates + cell update: one (batch, col) per thread; sum 4 kq partials ----
    float zi = bi, zg = bg, zf = bfg, zo = bo;
#pragma unroll
    for (int k2 = 0; k2 < 4; ++k2) {
      zi += Z4[k2][eb][     ej];
      zg += Z4[k2][eb][ 8 + ej];
      zf += Z4[k2][eb][16 + ej];
      zo += Z4[k2][eb][24 + ej];
    }
    float ig = sigmoidf_(zi);
    float g  = fmaxf(zg, 0.0f);
    float ff = sigmoidf_(zf);
    float oo = sigmoidf_(zo);
    cst = ff * cst + ig * g;
    float hn = oo * fmaxf(cst, 0.0f);
    Hl[eb][ej] = f2bf(hn);                                     // gather h(t) in LDS
    __syncthreads();                                           // (B) Hl ready, Z4 reads done

    // ---- wave 0 only: coalesced 16B h stores -> own vmcnt drain -> per-block flag ----
    if (tid < 64) {
      i32x4 hv = *(const i32x4*)(&Hl[tid][0]);                 // ds_read_b128
      llvm_amdgcn_raw_buffer_store_v4i32(hv, hsrd,
          t * (Bsz * Hn * 2) + (tid * Hn + blk * 8) * 2, 0, 17);
      asm volatile("s_waitcnt vmcnt(0)" ::: "memory");         // MALL-acked => visible
      if (tid == 0 && t < Tn - 1)
        llvm_amdgcn_raw_buffer_store_i32(t + 1, fsrd, blk << 2, 0, 17);
    }
    // Other waves proceed straight to step t+1 polling; barrier (A) of t+1 keeps
    // wave0's Hl reads ordered before the next Hl writes.
  }
}

// ---------------- dense epilogue: out[b,t,:] = hs_row @ Wd + bd ----------------
__global__ __launch_bounds__(256) void dense_kernel(
    const unsigned short* __restrict__ hs,    // [32768][1024] bf16, row = t*64+b
    const unsigned short* __restrict__ WdT,   // [128][1024] bf16
    const float* __restrict__ bd,             // [128]
    float* __restrict__ out)                  // [64][512][128] fp32
{
  const int tid = threadIdx.x;
  const int w = tid >> 6, l = tid & 63, q = l >> 4, n16 = l & 15;
  const int R0 = blockIdx.x * 64 + w * 16;
  f32x4 acc[8];
#pragma unroll
  for (int i = 0; i < 8; ++i) acc[i] = (f32x4){0, 0, 0, 0};
  const unsigned short* arow = hs + (size_t)(R0 + n16) * Hn + q * 8;
#pragma unroll 4
  for (int ks = 0; ks < 32; ++ks) {
    bf16x8 A = *(const bf16x8*)(arow + ks * 32);
#pragma unroll
    for (int nt = 0; nt < 8; ++nt) {
      bf16x8 Bf = *(const bf16x8*)(WdT + (size_t)(nt * 16 + n16) * Hn + ks * 32 + q * 8);
      acc[nt] = __builtin_amdgcn_mfma_f32_16x16x32_bf16(A, Bf, acc[nt], 0, 0, 0);
    }
  }
#pragma unroll
  for (int nt = 0; nt < 8; ++nt) {
    int col = nt * 16 + n16;
    float bdv = bd[col];
#pragma unroll
    for (int r = 0; r < 4; ++r) {
      int R = R0 + q * 4 + r;
      int b = R & 63, t = R >> 6;
      out[((size_t)b * Tn + t) * 128 + col] = acc[nt][r] + bdv;
    }
  }
}

// ---------------- launcher ----------------
extern "C" void kernel_launch(void* const* d_in, const int* in_sizes, int n_in,
                              void* d_out, int out_size, void* d_ws, size_t ws_size,
                              hipStream_t stream) {
  const float* X    = (const float*)d_in[0];   // [64][512][128]
  const float* Wk   = (const float*)d_in[1];   // [1152][4096]
  const float* bias = (const float*)d_in[2];   // [4096]
  const float* Wd   = (const float*)d_in[3];   // [1024][128]
  const float* bd   = (const float*)d_in[4];   // [128]
  float* out = (float*)d_out;

  // ws layout (bytes):
  char* ws = (char*)d_ws;
  unsigned short* Xb  = (unsigned short*)(ws);              //  8,388,608
  unsigned short* WkT = (unsigned short*)(ws + 8388608);    //  9,437,184
  unsigned short* WdT = (unsigned short*)(ws + 17825792);   //    262,144
  unsigned short* hs  = (unsigned short*)(ws + 18087936);   // 67,108,864
  unsigned*       syn = (unsigned*)      (ws + 85196800);   //      4,096 (sync area)

  hipMemsetAsync(syn, 0, 4096, stream);
  cast_x_kernel<<<4096, 256, 0, stream>>>(X, Xb);
  transpose_cast_kernel<<<1152, 256, 0, stream>>>(Wk, WkT, 1152, 4096, 1152, 18);
  transpose_cast_kernel<<<32, 256, 0, stream>>>(Wd, WdT, 1024, 128, 1024, 16);
  lstm_kernel<<<NBLK, 512, 0, stream>>>(Xb, WkT, bias, hs, syn);
  dense_kernel<<<512, 256, 0, stream>>>(hs, WdT, bd, out);
}

// Round 2
// 3601.749 us; speedup vs baseline: 1.1275x; 1.1275x over previous
//
#include <hip/hip_runtime.h>
#include <math.h>

// Problem: B=64, T=512, I=128, H=1024, O=128; gates order i,j,f,o; relu activations.
#define Bsz 64
#define Tn  512
#define In  128
#define Hn  1024
#define KT  1152      // I + H
#define NBLK 128      // persistent blocks; each owns 8 hidden cols (x4 gates = 32 cols)

// syn (u32 word indices), each hot word on its own 128B line:
//   group arrive counters: S[32*g], g=0..7 (monotone, 16 arrivals/step).
// Consumers poll the COUNTER directly (>= 16*t)  -> no separate flag post hop.
#define GARR0 0

typedef __attribute__((ext_vector_type(8))) short bf16x8;   // 8 bf16 = 4 VGPRs (MFMA A/B frag)
typedef __attribute__((ext_vector_type(4))) short s16x4;
typedef __attribute__((ext_vector_type(4))) float f32x4;
typedef __attribute__((ext_vector_type(4))) int   i32x4;

// Raw buffer store, cpol 17 = SC0|SC1 on gfx950 -> write-through to the IF/MALL
// coherence point (cross-XCD visible without any cache-walk fences). [R2/R3-proven]
__device__ void llvm_amdgcn_raw_buffer_store_i16(short vdata, i32x4 srsrc, int voffset, int soffset, int cpol) __asm("llvm.amdgcn.raw.buffer.store.i16");

__device__ __forceinline__ i32x4 make_srd(const void* p, int bytes) {
  i32x4 r;
  r.x = (int)(unsigned)(unsigned long long)p;
  r.y = (int)((unsigned long long)p >> 32);   // stride = 0
  r.z = bytes;                                // num_records (bytes when stride==0)
  r.w = 0x00020000;                           // raw dword access
  return r;
}

__device__ __forceinline__ unsigned short f2bf(float f) {
  union { float f; unsigned u; } x; x.f = f;
  unsigned r = x.u + 0x7FFFu + ((x.u >> 16) & 1u);   // RNE
  return (unsigned short)(r >> 16);
}
__device__ __forceinline__ float sigmoidf_(float x) { return 1.0f / (1.0f + __expf(-x)); }

// ---------------- prep: X (fp32) -> Xb (bf16), elementwise ----------------
__global__ __launch_bounds__(256) void cast_x_kernel(const float* __restrict__ in,
                                                     unsigned short* __restrict__ out) {
  int i = blockIdx.x * 256 + threadIdx.x;
  f32x4 v = ((const f32x4*)in)[i];
  s16x4 o;
  o.x = (short)f2bf(v.x); o.y = (short)f2bf(v.y);
  o.z = (short)f2bf(v.z); o.w = (short)f2bf(v.w);
  ((s16x4*)out)[i] = o;
}

// -------- prep: transpose+cast fp32 [R][C] -> bf16 [C][ldo] (64x64 LDS tiles) --------
__global__ __launch_bounds__(256) void transpose_cast_kernel(const float* __restrict__ in,
                                                             unsigned short* __restrict__ out,
                                                             int R, int C, int ldo, int tilesR) {
  __shared__ unsigned short tile[64][73];
  int br = blockIdx.x % tilesR, bc = blockIdx.x / tilesR;
  int r0 = br << 6, c0 = bc << 6;
  for (int e = threadIdx.x; e < 4096; e += 256) {
    int r = e >> 6, c = e & 63;
    tile[r][c] = f2bf(in[(size_t)(r0 + r) * C + (c0 + c)]);
  }
  __syncthreads();
  for (int e = threadIdx.x; e < 4096; e += 256) {
    int c = e >> 6, r = e & 63;
    out[(size_t)(c0 + c) * ldo + (r0 + r)] = tile[r][c];
  }
}

// ---------------- persistent LSTM recurrence ----------------
// Block blk owns hidden cols j in [blk*8, blk*8+8), gate cols {j, H+j, 2H+j, 3H+j}.
// 8 waves = (2 batch-halves mh) x (4 K-quarters kq); B-frags register-resident.
//
// K re-slice (this round): wave kq owns x cols [32kq,32kq+32) + h cols [256kq,256kq+256)
//   -> every wave: 9 uniform k-steps (1 x-step + 8 h-steps),
//   -> every wave depends on EXACTLY 2 producer groups {2kq, 2kq+1},
//   -> every wave prefetches its X slice before polling.
//
// Sync (R0-proven skeleton, minus one hop):
//   arrive: tid0 agent fetch_add on group counter (grp = blk>>4, 16 blocks/group).
//   wait:   lanes 0..1 of each wave poll its 2 group COUNTERS (>= 16t) with
//           ballot + s_sleep backoff. No flag post: counter IS the flag.
// h hand-off: sc1 write-through stores by all 512 threads (MALL-acked at the
// __syncthreads vmcnt drain BEFORE the arrive); consumer loads PLAIN -> per-XCD
// L2-shared, virgin t-lines.
__global__ __launch_bounds__(512, 1) void lstm_kernel(
    const unsigned short* __restrict__ Xb,    // [64][512][128] bf16
    const unsigned short* __restrict__ WkT,   // [4096][1152]  bf16 (col-major-in-k)
    const float* __restrict__ bias,           // [4096]
    unsigned short* __restrict__ hs,          // [512][64][1024] bf16 (output history)
    unsigned* __restrict__ S)                 // sync area (4 KB, zeroed)
{
  __shared__ float Z4[4][64][36];             // per-kq partials [kq][batch][32 cols], ld 36
  const int tid = threadIdx.x;
  const int blk = blockIdx.x;
  const int grp = blk >> 4;                   // 8 static groups of 16 blocks
  const int w   = tid >> 6;
  const int mh  = w & 1;                      // batch half (32 rows)
  const int kq  = w >> 1;                     // K quarter: x[32kq,+32) + h[256kq,+256)
  const int l   = tid & 63, q = l >> 4, n16 = l & 15;

  const i32x4 hsrd = make_srd(hs, Tn * Bsz * Hn * 2);

  // ---- load register-resident B fragments (once); k-layout matches the re-slice ----
  bf16x8 Bf[2][9];
#pragma unroll
  for (int nt = 0; nt < 2; ++nt) {
    int cl   = nt * 16 + n16;                                  // local col 0..31
    int gcol = (cl >> 3) * Hn + blk * 8 + (cl & 7);            // gate*1024 + j
    const unsigned short* bp = WkT + (size_t)gcol * KT;
    Bf[nt][0] = *(const bf16x8*)(bp + kq * 32 + q * 8);        // x slice
#pragma unroll
    for (int ks = 1; ks < 9; ++ks)                             // h slice
      Bf[nt][ks] = *(const bf16x8*)(bp + 128 + kq * 256 + (ks - 1) * 32 + q * 8);
  }

  // ---- epilogue constants: thread = (batch eb, col ej) ----
  const int eb = tid >> 3, ej = tid & 7;
  const float bi  = bias[           blk * 8 + ej];
  const float bg  = bias[    Hn   + blk * 8 + ej];
  const float bfg = bias[2 * Hn   + blk * 8 + ej] + 1.0f;      // TF forget bias
  const float bo  = bias[3 * Hn   + blk * 8 + ej];
  const int   hst_off = (eb * Hn + blk * 8 + ej) * 2;          // per-thread h store (byte, sans t)
  float cst = 0.0f;                                            // cell state, persistent in VGPR

  const int b0 = mh * 32 + n16;                                // A rows (two 16-batch tiles)
  const int b1 = b0 + 16;

  for (int t = 0; t < Tn; ++t) {
    f32x4 a00 = {0,0,0,0}, a01 = {0,0,0,0}, a10 = {0,0,0,0}, a11 = {0,0,0,0};

    // x-part A-frags never depend on flags: prefetch before polling (ALL waves)
    bf16x8 X0 = *(const bf16x8*)(Xb + ((size_t)b0 * Tn + t) * In + kq * 32 + q * 8);
    bf16x8 X1 = *(const bf16x8*)(Xb + ((size_t)b1 * Tn + t) * In + kq * 32 + q * 8);

    if (t > 0) {
      // wave-local wait: lanes 0,1 poll this wave's 2 producer-group counters.
      // counter >= 16*t  <=>  all 16 blocks of that group finished step t-1.
      const unsigned tgt = 16u * (unsigned)t;
      for (;;) {
        unsigned f = (l < 2) ? __hip_atomic_load(&S[GARR0 + 32 * (2 * kq + l)],
                                                 __ATOMIC_RELAXED, __HIP_MEMORY_SCOPE_AGENT)
                             : 0xFFFFFFFFu;
        if (__ballot(f >= tgt) == ~0ull) break;
        __builtin_amdgcn_s_sleep(1);          // ~64cy backoff: pace the MALL poll storm
      }
      const unsigned short* hrow = hs + (size_t)(t - 1) * (Bsz * Hn);
      a00 = __builtin_amdgcn_mfma_f32_16x16x32_bf16(X0, Bf[0][0], a00, 0, 0, 0);
      a01 = __builtin_amdgcn_mfma_f32_16x16x32_bf16(X0, Bf[1][0], a01, 0, 0, 0);
      a10 = __builtin_amdgcn_mfma_f32_16x16x32_bf16(X1, Bf[0][0], a10, 0, 0, 0);
      a11 = __builtin_amdgcn_mfma_f32_16x16x32_bf16(X1, Bf[1][0], a11, 0, 0, 0);
#pragma unroll
      for (int ks = 1; ks < 9; ++ks) {
        int kh = kq * 256 + (ks - 1) * 32 + q * 8;             // h col
        bf16x8 A0 = *(const bf16x8*)(hrow + (size_t)b0 * Hn + kh);
        bf16x8 A1 = *(const bf16x8*)(hrow + (size_t)b1 * Hn + kh);
        a00 = __builtin_amdgcn_mfma_f32_16x16x32_bf16(A0, Bf[0][ks], a00, 0, 0, 0);
        a01 = __builtin_amdgcn_mfma_f32_16x16x32_bf16(A0, Bf[1][ks], a01, 0, 0, 0);
        a10 = __builtin_amdgcn_mfma_f32_16x16x32_bf16(A1, Bf[0][ks], a10, 0, 0, 0);
        a11 = __builtin_amdgcn_mfma_f32_16x16x32_bf16(A1, Bf[1][ks], a11, 0, 0, 0);
      }
    } else {                                                   // t==0: h==0, x-part only
      a00 = __builtin_amdgcn_mfma_f32_16x16x32_bf16(X0, Bf[0][0], a00, 0, 0, 0);
      a01 = __builtin_amdgcn_mfma_f32_16x16x32_bf16(X0, Bf[1][0], a01, 0, 0, 0);
      a10 = __builtin_amdgcn_mfma_f32_16x16x32_bf16(X1, Bf[0][0], a10, 0, 0, 0);
      a11 = __builtin_amdgcn_mfma_f32_16x16x32_bf16(X1, Bf[1][0], a11, 0, 0, 0);
    }

    // ---- write per-kq partials (no atomics) ----
#pragma unroll
    for (int r = 0; r < 4; ++r) {
      int row = mh * 32 + q * 4 + r;
      Z4[kq][row     ][     n16] = a00[r];
      Z4[kq][row     ][16 + n16] = a01[r];
      Z4[kq][row + 16][     n16] = a10[r];
      Z4[kq][row + 16][16 + n16] = a11[r];
    }
    __syncthreads();

    // ---- gates + cell update: one (batch, col) per thread; sum 4 kq partials ----
    float zi = bi, zg = bg, zf = bfg, zo = bo;
#pragma unroll
    for (int k2 = 0; k2 < 4; ++k2) {
      zi += Z4[k2][eb][     ej];
      zg += Z4[k2][eb][ 8 + ej];
      zf += Z4[k2][eb][16 + ej];
      zo += Z4[k2][eb][24 + ej];
    }
    float ig = sigmoidf_(zi);
    float g  = fmaxf(zg, 0.0f);
    float ff = sigmoidf_(zf);
    float oo = sigmoidf_(zo);
    cst = ff * cst + ig * g;
    float hn = oo * fmaxf(cst, 0.0f);
    llvm_amdgcn_raw_buffer_store_i16((short)f2bf(hn), hsrd,
                                     t * (Bsz * Hn * 2) + hst_off, 0, 17);

    // __syncthreads drains every wave's vmcnt(0): sc1 store acks come from the
    // coherence point, so h(t) is globally visible before the arrive below.
    __syncthreads();
    if (t < Tn - 1 && tid == 0) {
      (void)__hip_atomic_fetch_add(&S[GARR0 + 32 * grp], 1u,
                                   __ATOMIC_RELAXED, __HIP_MEMORY_SCOPE_AGENT);
    }
  }
}

// ---------------- dense epilogue: out[b,t,:] = hs_row @ Wd + bd ----------------
__global__ __launch_bounds__(256) void dense_kernel(
    const unsigned short* __restrict__ hs,    // [32768][1024] bf16, row = t*64+b
    const unsigned short* __restrict__ WdT,   // [128][1024] bf16
    const float* __restrict__ bd,             // [128]
    float* __restrict__ out)                  // [64][512][128] fp32
{
  const int tid = threadIdx.x;
  const int w = tid >> 6, l = tid & 63, q = l >> 4, n16 = l & 15;
  const int R0 = blockIdx.x * 64 + w * 16;
  f32x4 acc[8];
#pragma unroll
  for (int i = 0; i < 8; ++i) acc[i] = (f32x4){0, 0, 0, 0};
  const unsigned short* arow = hs + (size_t)(R0 + n16) * Hn + q * 8;
#pragma unroll 4
  for (int ks = 0; ks < 32; ++ks) {
    bf16x8 A = *(const bf16x8*)(arow + ks * 32);
#pragma unroll
    for (int nt = 0; nt < 8; ++nt) {
      bf16x8 Bf = *(const bf16x8*)(WdT + (size_t)(nt * 16 + n16) * Hn + ks * 32 + q * 8);
      acc[nt] = __builtin_amdgcn_mfma_f32_16x16x32_bf16(A, Bf, acc[nt], 0, 0, 0);
    }
  }
#pragma unroll
  for (int nt = 0; nt < 8; ++nt) {
    int col = nt * 16 + n16;
    float bdv = bd[col];
#pragma unroll
    for (int r = 0; r < 4; ++r) {
      int R = R0 + q * 4 + r;
      int b = R & 63, t = R >> 6;
      out[((size_t)b * Tn + t) * 128 + col] = acc[nt][r] + bdv;
    }
  }
}

// ---------------- launcher ----------------
extern "C" void kernel_launch(void* const* d_in, const int* in_sizes, int n_in,
                              void* d_out, int out_size, void* d_ws, size_t ws_size,
                              hipStream_t stream) {
  const float* X    = (const float*)d_in[0];   // [64][512][128]
  const float* Wk   = (const float*)d_in[1];   // [1152][4096]
  const float* bias = (const float*)d_in[2];   // [4096]
  const float* Wd   = (const float*)d_in[3];   // [1024][128]
  const float* bd   = (const float*)d_in[4];   // [128]
  float* out = (float*)d_out;

  // ws layout (bytes):
  char* ws = (char*)d_ws;
  unsigned short* Xb  = (unsigned short*)(ws);              //  8,388,608
  unsigned short* WkT = (unsigned short*)(ws + 8388608);    //  9,437,184
  unsigned short* WdT = (unsigned short*)(ws + 17825792);   //    262,144
  unsigned short* hs  = (unsigned short*)(ws + 18087936);   // 67,108,864
  unsigned*       syn = (unsigned*)      (ws + 85196800);   //      4,096 (sync area)

  hipMemsetAsync(syn, 0, 4096, stream);
  cast_x_kernel<<<4096, 256, 0, stream>>>(X, Xb);
  transpose_cast_kernel<<<1152, 256, 0, stream>>>(Wk, WkT, 1152, 4096, 1152, 18);
  transpose_cast_kernel<<<32, 256, 0, stream>>>(Wd, WdT, 1024, 128, 1024, 16);
  lstm_kernel<<<NBLK, 512, 0, stream>>>(Xb, WkT, bias, hs, syn);
  dense_kernel<<<512, 256, 0, stream>>>(hs, WdT, bd, out);
}